// Round 6
// baseline (469.278 us; speedup 1.0000x reference)
//
#include <hip/hip_runtime.h>
#include <hip/hip_bf16.h>
#include <stdint.h>

#define T_STEPS 16
#define BATCH   16
#define CHANNELS 32
#define HGT 128
#define WID 128
#define HW (HGT*WID)      // 16384
#define KSEL 8192         // ascending 0-based rank of threshold = N - k
#define CAP 1024          // candidate buffer size (safety)
#define SMALL 128         // stop narrowing when candidate set <= SMALL

typedef float vfloat4 __attribute__((ext_vector_type(4)));
typedef float vfloat2 __attribute__((ext_vector_type(2)));

// ---------- kernel 1: channel max pool (memory-bound streamer) ----------
__global__ __launch_bounds__(256)
void pool_max_kernel(const float* __restrict__ x, float* __restrict__ pooled) {
    int tid  = blockIdx.x * blockDim.x + threadIdx.x;   // 1,048,576 threads
    int base = tid * 4;                                 // pooled element index
    int tb   = base >> 14;                              // /HW
    int pix  = base & (HW - 1);
    const vfloat4* src = (const vfloat4*)(x + (size_t)tb * CHANNELS * HW + pix);
    vfloat4 m = __builtin_nontemporal_load(src);
    #pragma unroll
    for (int c = 1; c < CHANNELS; ++c) {
        vfloat4 v = __builtin_nontemporal_load(src + (size_t)c * (HW/4));
        m.x = fmaxf(m.x, v.x); m.y = fmaxf(m.y, v.y);
        m.z = fmaxf(m.z, v.z); m.w = fmaxf(m.w, v.w);
    }
    *(vfloat4*)(pooled + base) = m;
}

// ---------- kernel 2: lif0, 256 thr x 64 elems, exact histogram select ----------
__global__ __launch_bounds__(256)
void lif0_kernel(const float* __restrict__ pooled, uint8_t* __restrict__ spk) {
    __shared__ uint32_t hist[4][260];    // per-wave rows, padded
    __shared__ uint32_t s_tot[256];      // merged histogram
    __shared__ float    col[CAP];
    __shared__ uint32_t s_sel[4];        // jsel, r_new, cnt_new, collect-counter
    __shared__ float    s_thr;

    const int b    = blockIdx.x;
    const int tid  = threadIdx.x;
    const int wid  = tid >> 6;           // 0..3
    const int lane = tid & 63;
    uint32_t* hflat = &hist[0][0];       // 1040 words

    float m[64];
    #pragma unroll
    for (int i = 0; i < 64; ++i) m[i] = 0.0f;

    for (int t = 0; t < T_STEPS; ++t) {
        // ---- integrate: mem = 0.25*mem + x (bit-identical to ref) ----
        const float4* p4 = (const float4*)(pooled + ((size_t)t * BATCH + b) * HW);
        #pragma unroll
        for (int i = 0; i < 16; ++i) {
            float4 v = p4[i * 256 + tid];
            m[i*4+0] = 0.25f * m[i*4+0] + v.x;
            m[i*4+1] = 0.25f * m[i*4+1] + v.y;
            m[i*4+2] = 0.25f * m[i*4+2] + v.z;
            m[i*4+3] = 0.25f * m[i*4+3] + v.w;
        }

        float    rlo   = 0.0f;
        float    scale = 64.0f;          // 256 bins over [0,4): hot bin ~270
        uint32_t r     = KSEL;
        uint32_t cnt;
        int      jsel;

        // ======== iteration 1: dense histogram with bin packing ========
        // clear 4x260 rows
        for (int j = tid; j < 4 * 260; j += 256) hflat[j] = 0;
        __syncthreads();
        uint32_t binpack[16];
        #pragma unroll
        for (int i = 0; i < 16; ++i) {
            uint32_t bp = 0;
            #pragma unroll
            for (int c = 0; c < 4; ++c) {
                int bn = (int)((m[i*4+c] - rlo) * scale);
                bn = min(max(bn, 0), 255);
                atomicAdd(&hist[wid][bn], 1u);
                bp |= (uint32_t)bn << (8 * c);
            }
            binpack[i] = bp;
        }
        __syncthreads();
        // merge 4 rows
        {
            uint32_t s = hist[0][tid] + hist[1][tid] + hist[2][tid] + hist[3][tid];
            s_tot[tid] = s;
        }
        __syncthreads();
        // wave 0: scan 256 bins (4/lane), pick bin containing rank r
        if (wid == 0) {
            uint32_t c[4], lsum = 0;
            #pragma unroll
            for (int q = 0; q < 4; ++q) { c[q] = s_tot[lane * 4 + q]; lsum += c[q]; }
            uint32_t inc = lsum;
            #pragma unroll
            for (int off = 1; off < 64; off <<= 1) {
                uint32_t v = __shfl_up(inc, off, 64);
                if (lane >= off) inc += v;
            }
            uint32_t acc = inc - lsum;
            int dsel = -1; uint32_t nr = 0, nc = 0;
            #pragma unroll
            for (int q = 0; q < 4; ++q) {
                if (dsel < 0 && r >= acc && r < acc + c[q]) {
                    dsel = lane * 4 + q; nr = r - acc; nc = c[q];
                }
                acc += c[q];
            }
            if (dsel >= 0) { s_sel[0] = (uint32_t)dsel; s_sel[1] = nr; s_sel[2] = nc; }
            if (tid == 0) s_sel[3] = 0;
        }
        __syncthreads();
        jsel = (int)s_sel[0]; r = s_sel[1]; cnt = s_sel[2];
        // filter via packed bins -> alive mask
        uint64_t amask = 0;
        #pragma unroll
        for (int i = 0; i < 16; ++i) {
            uint32_t bp = binpack[i];
            #pragma unroll
            for (int c = 0; c < 4; ++c)
                if (((bp >> (8 * c)) & 255u) == (uint32_t)jsel)
                    amask |= 1ull << (i * 4 + c);
        }
        rlo   = rlo + (float)jsel / scale;
        scale = scale * 256.0f;

        // ======== iterations 2+: sparse (visit only alive elements) ========
        for (int iter = 1; cnt > SMALL && iter < 6; ++iter) {
            for (int j = tid; j < 4 * 260; j += 256) hflat[j] = 0;
            __syncthreads();
            for (uint64_t tm = amask; tm; tm &= tm - 1) {
                int j = __builtin_ctzll(tm);
                int bn = (int)((m[j] - rlo) * scale);
                bn = min(max(bn, 0), 255);
                atomicAdd(&hist[wid][bn], 1u);
            }
            __syncthreads();
            {
                uint32_t s = hist[0][tid] + hist[1][tid] + hist[2][tid] + hist[3][tid];
                s_tot[tid] = s;
            }
            __syncthreads();
            if (wid == 0) {
                uint32_t c[4], lsum = 0;
                #pragma unroll
                for (int q = 0; q < 4; ++q) { c[q] = s_tot[lane * 4 + q]; lsum += c[q]; }
                uint32_t inc = lsum;
                #pragma unroll
                for (int off = 1; off < 64; off <<= 1) {
                    uint32_t v = __shfl_up(inc, off, 64);
                    if (lane >= off) inc += v;
                }
                uint32_t acc = inc - lsum;
                int dsel = -1; uint32_t nr = 0, nc = 0;
                #pragma unroll
                for (int q = 0; q < 4; ++q) {
                    if (dsel < 0 && r >= acc && r < acc + c[q]) {
                        dsel = lane * 4 + q; nr = r - acc; nc = c[q];
                    }
                    acc += c[q];
                }
                if (dsel >= 0) { s_sel[0] = (uint32_t)dsel; s_sel[1] = nr; s_sel[2] = nc; }
                if (tid == 0) s_sel[3] = 0;
            }
            __syncthreads();
            jsel = (int)s_sel[0]; r = s_sel[1]; cnt = s_sel[2];
            for (uint64_t tm = amask; tm; tm &= tm - 1) {
                int j = __builtin_ctzll(tm);
                int bn = (int)((m[j] - rlo) * scale);
                bn = min(max(bn, 0), 255);
                if (bn != jsel) amask &= ~(1ull << j);
            }
            rlo   = rlo + (float)jsel / scale;
            scale = scale * 256.0f;
        }

        // ---- collect candidates: wave scan + 1 atomic per wave ----
        {
            uint32_t myc  = (uint32_t)__builtin_popcountll(amask);
            uint32_t incl = myc;
            #pragma unroll
            for (int off = 1; off < 64; off <<= 1) {
                uint32_t v = __shfl_up(incl, off, 64);
                if (lane >= off) incl += v;
            }
            uint32_t wtot = __shfl(incl, 63, 64);
            uint32_t base = 0;
            if (lane == 63) base = atomicAdd(&s_sel[3], wtot);
            base = __shfl(base, 63, 64);
            uint32_t off = base + incl - myc;
            for (uint64_t tm = amask; tm; tm &= tm - 1) {
                int j = __builtin_ctzll(tm);
                if (off < CAP) col[off] = m[j];
                ++off;
            }
        }
        __syncthreads();
        // ---- exact rank-select among candidates ----
        {
            uint32_t ncol = min(cnt, (uint32_t)CAP);
            for (uint32_t j = tid; j < ncol; j += 256) {
                float v = col[j];
                uint32_t less = 0, leq = 0;
                for (uint32_t i = 0; i < ncol; ++i) {
                    float u = col[i];
                    less += (u < v);
                    leq  += (u <= v);
                }
                if (less <= r && r < leq) s_thr = v;   // k-th largest, exact bits
            }
        }
        __syncthreads();
        const float thr = s_thr;

        // ---- spikes + hard reset ----
        uchar4* so4 = (uchar4*)(spk + ((size_t)t * BATCH + b) * HW);
        #pragma unroll
        for (int i = 0; i < 16; ++i) {
            uchar4 s4;
            s4.x = (m[i*4+0] >= thr) ? 1 : 0;
            s4.y = (m[i*4+1] >= thr) ? 1 : 0;
            s4.z = (m[i*4+2] >= thr) ? 1 : 0;
            s4.w = (m[i*4+3] >= thr) ? 1 : 0;
            if (s4.x) m[i*4+0] = 0.0f;
            if (s4.y) m[i*4+1] = 0.0f;
            if (s4.z) m[i*4+2] = 0.0f;
            if (s4.w) m[i*4+3] = 0.0f;
            so4[i * 256 + tid] = s4;
        }
        __syncthreads();   // protect LDS reuse next t
    }
}

// ---------- kernel 3: fused 7x7 conv (cross-correlation) + lif1 ----------
__global__ __launch_bounds__(256)
void conv_lif1_kernel(const uint8_t* __restrict__ spk, const float* __restrict__ wconv,
                      float* __restrict__ out_spike, float* __restrict__ out_mem) {
    __shared__ float tile[14][136];  // 8-row stripe + 3 halo each side
    const int bidx   = blockIdx.x;   // 0..255
    const int b      = bidx >> 4;
    const int stripe = bidx & 15;
    const int r0     = stripe * 8;
    const int tid    = threadIdx.x;
    const int sr     = tid >> 5;           // 0..7
    const int c0     = (tid & 31) << 2;    // 0,4,...,124

    float w[49];
    #pragma unroll
    for (int i = 0; i < 49; ++i) w[i] = wconv[i];   // uniform -> scalar regs

    float mem[4] = {0.0f, 0.0f, 0.0f, 0.0f};

    for (int t = 0; t < T_STEPS; ++t) {
        __syncthreads();   // tile reuse guard
        const uint8_t* sp = spk + ((size_t)t * BATCH + b) * HW;
        for (int k = tid; k < 14 * 134; k += 256) {
            int row  = k / 134;
            int colp = k - row * 134;
            int gr = r0 - 3 + row;
            int gc = colp - 3;
            float v = 0.0f;
            if ((unsigned)gr < HGT && (unsigned)gc < WID)
                v = (float)sp[gr * WID + gc];
            tile[row][colp] = v;
        }
        __syncthreads();
        float a0 = 0.f, a1 = 0.f, a2 = 0.f, a3 = 0.f;
        #pragma unroll
        for (int dy = 0; dy < 7; ++dy) {
            const float* rowp = &tile[sr + dy][c0];
            vfloat4 u = *(const vfloat4*)rowp;
            vfloat4 v = *(const vfloat4*)(rowp + 4);
            vfloat2 e = *(const vfloat2*)(rowp + 8);
            float r[10] = {u.x,u.y,u.z,u.w, v.x,v.y,v.z,v.w, e.x,e.y};
            #pragma unroll
            for (int dx = 0; dx < 7; ++dx) {
                float wv = w[dy * 7 + dx];
                a0 = fmaf(r[dx + 0], wv, a0);
                a1 = fmaf(r[dx + 1], wv, a1);
                a2 = fmaf(r[dx + 2], wv, a2);
                a3 = fmaf(r[dx + 3], wv, a3);
            }
        }
        float m0 = 0.25f * mem[0] + a0;
        float m1 = 0.25f * mem[1] + a1;
        float m2 = 0.25f * mem[2] + a2;
        float m3 = 0.25f * mem[3] + a3;
        float s0 = (m0 > 1.0f) ? 1.0f : 0.0f;
        float s1 = (m1 > 1.0f) ? 1.0f : 0.0f;
        float s2 = (m2 > 1.0f) ? 1.0f : 0.0f;
        float s3 = (m3 > 1.0f) ? 1.0f : 0.0f;
        size_t o = (((size_t)t * BATCH + b) << 14) + (size_t)(r0 + sr) * WID + c0;
        vfloat4 sv = {s0, s1, s2, s3};
        vfloat4 mv = {m0, m1, m2, m3};
        *(vfloat4*)(out_spike + o) = sv;
        *(vfloat4*)(out_mem   + o) = mv;
        mem[0] = m0 - s0; mem[1] = m1 - s1; mem[2] = m2 - s2; mem[3] = m3 - s3;
    }
}

extern "C" void kernel_launch(void* const* d_in, const int* in_sizes, int n_in,
                              void* d_out, int out_size, void* d_ws, size_t ws_size,
                              hipStream_t stream) {
    const float* x     = (const float*)d_in[0];
    const float* wconv = (const float*)d_in[1];
    float* out = (float*)d_out;

    const size_t n_pooled = (size_t)T_STEPS * BATCH * HW;     // 4,194,304
    float*   pooled = (float*)d_ws;
    uint8_t* spk    = (uint8_t*)d_ws + n_pooled * sizeof(float);

    pool_max_kernel<<<4096, 256, 0, stream>>>(x, pooled);
    // TIMING INSTRUMENT: lif0 launched TWICE (idempotent — state re-inited
    // in-kernel). dur(this round) - dur(next round, single launch) = lif0 cost.
    lif0_kernel<<<BATCH, 256, 0, stream>>>(pooled, spk);
    lif0_kernel<<<BATCH, 256, 0, stream>>>(pooled, spk);
    conv_lif1_kernel<<<256, 256, 0, stream>>>(spk, wconv, out, out + n_pooled);
}

// Round 7
// 267.658 us; speedup vs baseline: 1.7533x; 1.7533x over previous
//
#include <hip/hip_runtime.h>
#include <hip/hip_bf16.h>
#include <stdint.h>

#define T_STEPS 16
#define BATCH   16
#define CHANNELS 32
#define HGT 128
#define WID 128
#define HW (HGT*WID)      // 16384
#define KSEL 8192         // ascending 0-based rank of threshold = N - k
#define CAP 1024          // candidate buffer (safety)
#define SMALL 128         // stop narrowing when candidate set <= SMALL
#define NB 4096           // histogram bins
#define NBS 1024.0f       // initial scale: 4096 bins over [0,4)

typedef float vfloat4 __attribute__((ext_vector_type(4)));
typedef float vfloat2 __attribute__((ext_vector_type(2)));

__device__ __forceinline__ vfloat4 v4max(vfloat4 a, vfloat4 b) {
    vfloat4 r;
    r.x = fmaxf(a.x, b.x); r.y = fmaxf(a.y, b.y);
    r.z = fmaxf(a.z, b.z); r.w = fmaxf(a.w, b.w);
    return r;
}

__device__ __forceinline__ uint32_t wave_incl_scan(uint32_t v, int lane) {
    #pragma unroll
    for (int off = 1; off < 64; off <<= 1) {
        uint32_t u = __shfl_up(v, off, 64);
        if (lane >= off) v += u;
    }
    return v;
}

// ---------- kernel 1: channel max pool (memory-bound streamer) ----------
// Plain (cached) loads — m13's 6.29 TB/s ceiling used plain float4 loads.
// 4 independent fmax chains for ILP.
__global__ __launch_bounds__(256)
void pool_max_kernel(const float* __restrict__ x, float* __restrict__ pooled) {
    int tid  = blockIdx.x * blockDim.x + threadIdx.x;   // 1,048,576 threads
    int base = tid * 4;
    int tb   = base >> 14;              // /HW
    int pix  = base & (HW - 1);
    const vfloat4* src = (const vfloat4*)(x + (size_t)tb * CHANNELS * HW + pix);
    vfloat4 a0 = src[0 * (HW/4)];
    vfloat4 a1 = src[1 * (HW/4)];
    vfloat4 a2 = src[2 * (HW/4)];
    vfloat4 a3 = src[3 * (HW/4)];
    #pragma unroll
    for (int c = 4; c < CHANNELS; c += 4) {
        a0 = v4max(a0, src[(c+0) * (HW/4)]);
        a1 = v4max(a1, src[(c+1) * (HW/4)]);
        a2 = v4max(a2, src[(c+2) * (HW/4)]);
        a3 = v4max(a3, src[(c+3) * (HW/4)]);
    }
    *(vfloat4*)(pooled + base) = v4max(v4max(a0, a1), v4max(a2, a3));
}

// ---------- kernel 2: lif0 — 1024 thr, single 4096-bin histogram pass ----------
__global__ __launch_bounds__(1024)
void lif0_kernel(const float* __restrict__ pooled, uint8_t* __restrict__ spk) {
    __shared__ uint32_t hist[NB];        // 16 KB
    __shared__ uint32_t s_wtot[16];
    __shared__ float    col[CAP];
    __shared__ uint32_t s_sel[4];        // jsel, r_new, cnt_new, collect-counter
    __shared__ float    s_thr;

    const int b    = blockIdx.x;
    const int tid  = threadIdx.x;
    const int wid  = tid >> 6;
    const int lane = tid & 63;

    float m[16];
    #pragma unroll
    for (int i = 0; i < 16; ++i) m[i] = 0.0f;

    for (int t = 0; t < T_STEPS; ++t) {
        // ---- integrate: mem = 0.25*mem + x (bit-identical to ref) ----
        const float4* p4 = (const float4*)(pooled + ((size_t)t * BATCH + b) * HW);
        #pragma unroll
        for (int i = 0; i < 4; ++i) {
            float4 v = p4[i * 1024 + tid];
            m[i*4+0] = 0.25f * m[i*4+0] + v.x;
            m[i*4+1] = 0.25f * m[i*4+1] + v.y;
            m[i*4+2] = 0.25f * m[i*4+2] + v.z;
            m[i*4+3] = 0.25f * m[i*4+3] + v.w;
        }

        // ---- exact select of ascending rank KSEL ----
        float    rlo   = 0.0f;
        float    sc    = NBS;            // 4096 bins over [0,4): hot bin ~20
        uint32_t r     = KSEL;
        uint32_t cnt   = HW;
        uint32_t amask = 0xFFFFu;
        int      iter  = 0;
        for (;;) {
            hist[tid] = 0; hist[tid + 1024] = 0; hist[tid + 2048] = 0; hist[tid + 3072] = 0;
            __syncthreads();
            #pragma unroll
            for (int i = 0; i < 16; ++i) {
                if (amask & (1u << i)) {
                    int bn = (int)((m[i] - rlo) * sc);
                    bn = min(max(bn, 0), NB - 1);
                    atomicAdd(&hist[bn], 1u);
                }
            }
            __syncthreads();
            // rank scan: thread owns bins [4tid, 4tid+4)
            uint4 hc = *(const uint4*)&hist[tid * 4];
            uint32_t psum = hc.x + hc.y + hc.z + hc.w;
            uint32_t incl = wave_incl_scan(psum, lane);
            if (lane == 63) s_wtot[wid] = incl;
            __syncthreads();
            uint32_t wbase = 0;
            for (int w = 0; w < wid; ++w) wbase += s_wtot[w];
            uint32_t excl = wbase + incl - psum;     // elements in bins < 4tid
            if (tid == 0) s_sel[3] = 0;
            if (r >= excl && r < excl + psum) {      // exactly one thread hits
                uint32_t cq[4] = {hc.x, hc.y, hc.z, hc.w};
                uint32_t acc = excl; int dsel = -1; uint32_t nr = 0, nc = 0;
                #pragma unroll
                for (int q = 0; q < 4; ++q) {
                    if (dsel < 0 && r < acc + cq[q]) { dsel = tid * 4 + q; nr = r - acc; nc = cq[q]; }
                    acc += cq[q];
                }
                s_sel[0] = (uint32_t)dsel; s_sel[1] = nr; s_sel[2] = nc;
            }
            __syncthreads();
            const int jsel = (int)s_sel[0];
            r = s_sel[1]; cnt = s_sel[2];
            // filter alive set (identical bin expression -> exact)
            uint32_t nm = 0;
            #pragma unroll
            for (int i = 0; i < 16; ++i) {
                if (amask & (1u << i)) {
                    int bn = (int)((m[i] - rlo) * sc);
                    bn = min(max(bn, 0), NB - 1);
                    if (bn == jsel) nm |= (1u << i);
                }
            }
            amask = nm;
            rlo += (float)jsel / sc;
            sc  *= (float)NB;
            if (cnt <= SMALL || ++iter >= 4) break;
        }

        // ---- collect candidates (~20 atomics total) ----
        #pragma unroll
        for (int i = 0; i < 16; ++i) {
            if (amask & (1u << i)) {
                uint32_t u = atomicAdd(&s_sel[3], 1u);
                if (u < CAP) col[u] = m[i];
            }
        }
        __syncthreads();
        // ---- exact rank-select among candidates ----
        {
            uint32_t ncol = min(cnt, (uint32_t)CAP);
            for (uint32_t j = tid; j < ncol; j += 1024) {
                float v = col[j];
                uint32_t less = 0, leq = 0;
                for (uint32_t i2 = 0; i2 < ncol; ++i2) {
                    float u = col[i2];
                    less += (u < v);
                    leq  += (u <= v);
                }
                if (less <= r && r < leq) s_thr = v;   // k-th largest, exact bits
            }
        }
        __syncthreads();
        const float thr = s_thr;

        // ---- spikes + hard reset ----
        uchar4* so4 = (uchar4*)(spk + ((size_t)t * BATCH + b) * HW);
        #pragma unroll
        for (int i = 0; i < 4; ++i) {
            uchar4 s4;
            s4.x = (m[i*4+0] >= thr) ? 1 : 0;
            s4.y = (m[i*4+1] >= thr) ? 1 : 0;
            s4.z = (m[i*4+2] >= thr) ? 1 : 0;
            s4.w = (m[i*4+3] >= thr) ? 1 : 0;
            if (s4.x) m[i*4+0] = 0.0f;
            if (s4.y) m[i*4+1] = 0.0f;
            if (s4.z) m[i*4+2] = 0.0f;
            if (s4.w) m[i*4+3] = 0.0f;
            so4[i * 1024 + tid] = s4;
        }
        __syncthreads();   // protect LDS reuse next t
    }
}

// ---------- kernel 3: fused 7x7 conv (cross-correlation) + lif1 ----------
__global__ __launch_bounds__(256)
void conv_lif1_kernel(const uint8_t* __restrict__ spk, const float* __restrict__ wconv,
                      float* __restrict__ out_spike, float* __restrict__ out_mem) {
    __shared__ float tile[14][136];  // 8-row stripe + 3 halo each side
    const int bidx   = blockIdx.x;   // 0..255
    const int b      = bidx >> 4;
    const int stripe = bidx & 15;
    const int r0     = stripe * 8;
    const int tid    = threadIdx.x;
    const int sr     = tid >> 5;           // 0..7
    const int c0     = (tid & 31) << 2;    // 0,4,...,124

    float w[49];
    #pragma unroll
    for (int i = 0; i < 49; ++i) w[i] = wconv[i];   // uniform -> scalar regs

    float mem[4] = {0.0f, 0.0f, 0.0f, 0.0f};

    for (int t = 0; t < T_STEPS; ++t) {
        __syncthreads();   // tile reuse guard
        const uint8_t* sp = spk + ((size_t)t * BATCH + b) * HW;
        for (int k = tid; k < 14 * 134; k += 256) {
            int row  = k / 134;
            int colp = k - row * 134;
            int gr = r0 - 3 + row;
            int gc = colp - 3;
            float v = 0.0f;
            if ((unsigned)gr < HGT && (unsigned)gc < WID)
                v = (float)sp[gr * WID + gc];
            tile[row][colp] = v;
        }
        __syncthreads();
        float a0 = 0.f, a1 = 0.f, a2 = 0.f, a3 = 0.f;
        #pragma unroll
        for (int dy = 0; dy < 7; ++dy) {
            const float* rowp = &tile[sr + dy][c0];
            vfloat4 u = *(const vfloat4*)rowp;
            vfloat4 v = *(const vfloat4*)(rowp + 4);
            vfloat2 e = *(const vfloat2*)(rowp + 8);
            float r[10] = {u.x,u.y,u.z,u.w, v.x,v.y,v.z,v.w, e.x,e.y};
            #pragma unroll
            for (int dx = 0; dx < 7; ++dx) {
                float wv = w[dy * 7 + dx];
                a0 = fmaf(r[dx + 0], wv, a0);
                a1 = fmaf(r[dx + 1], wv, a1);
                a2 = fmaf(r[dx + 2], wv, a2);
                a3 = fmaf(r[dx + 3], wv, a3);
            }
        }
        float m0 = 0.25f * mem[0] + a0;
        float m1 = 0.25f * mem[1] + a1;
        float m2 = 0.25f * mem[2] + a2;
        float m3 = 0.25f * mem[3] + a3;
        float s0 = (m0 > 1.0f) ? 1.0f : 0.0f;
        float s1 = (m1 > 1.0f) ? 1.0f : 0.0f;
        float s2 = (m2 > 1.0f) ? 1.0f : 0.0f;
        float s3 = (m3 > 1.0f) ? 1.0f : 0.0f;
        size_t o = (((size_t)t * BATCH + b) << 14) + (size_t)(r0 + sr) * WID + c0;
        vfloat4 sv = {s0, s1, s2, s3};
        vfloat4 mv = {m0, m1, m2, m3};
        *(vfloat4*)(out_spike + o) = sv;
        *(vfloat4*)(out_mem   + o) = mv;
        mem[0] = m0 - s0; mem[1] = m1 - s1; mem[2] = m2 - s2; mem[3] = m3 - s3;
    }
}

extern "C" void kernel_launch(void* const* d_in, const int* in_sizes, int n_in,
                              void* d_out, int out_size, void* d_ws, size_t ws_size,
                              hipStream_t stream) {
    const float* x     = (const float*)d_in[0];
    const float* wconv = (const float*)d_in[1];
    float* out = (float*)d_out;

    const size_t n_pooled = (size_t)T_STEPS * BATCH * HW;     // 4,194,304
    float*   pooled = (float*)d_ws;
    uint8_t* spk    = (uint8_t*)d_ws + n_pooled * sizeof(float);

    pool_max_kernel<<<4096, 256, 0, stream>>>(x, pooled);
    lif0_kernel<<<BATCH, 1024, 0, stream>>>(pooled, spk);
    conv_lif1_kernel<<<256, 256, 0, stream>>>(spk, wconv, out, out + n_pooled);
}